// Round 11
// baseline (782.439 us; speedup 1.0000x reference)
//
#include <hip/hip_runtime.h>

// WeightOnlyInt4Linear: out[8192,11008] = x[8192,4096] @ dequant(packed int4 W)
// (1) x -> bf16, (2) W int4 -> bf16 [N][K] transposed, (3) 256x256 bf16 MFMA GEMM.
// R11: double-buffer LDS (128 KB) with ONE s_barrier + ONE vmcnt(0) per K-tile.
// All stages (into sb) are placed AFTER the tile's p0 BAR -> WAR-safe vs every
// wave's t-1 reads; reads (from buf) covered by p0-top WAITV(0) (queue = tile t's
// 8 loads only, all >=1 phase old). p1-p3 are barrier-free: {stage, ds_read,
// lgkmcnt(0), 16 MFMA}. Waves drift up to a full K-tile -> max MFMA overlap.

#define M_DIM 8192
#define K_DIM 4096
#define N_DIM 11008
#define BM 256
#define BN 256
#define BK 64
#define NKT (K_DIM / BK)  // 64

typedef unsigned short u16;
typedef __bf16 bf16x8 __attribute__((ext_vector_type(8)));
typedef float floatx4 __attribute__((ext_vector_type(4)));
typedef u16 u16x8 __attribute__((ext_vector_type(8)));
typedef u16 u16x4 __attribute__((ext_vector_type(4)));

typedef __attribute__((address_space(1))) const void* gcvp;
typedef __attribute__((address_space(3))) void* svp;

static __device__ __forceinline__ u16 f2b(float f) {
  union { float f; unsigned u; } v;
  v.f = f;
  unsigned r = v.u + 0x7FFFu + ((v.u >> 16) & 1u);  // RNE, finite inputs
  return (u16)(r >> 16);
}

// ---------------- kernel 1: x f32 -> bf16 ----------------
__global__ __launch_bounds__(256) void cvt_x_kernel(const float* __restrict__ x,
                                                    u16* __restrict__ xb) {
  int i = blockIdx.x * 256 + threadIdx.x;
  const int n4 = (M_DIM * K_DIM) / 4;
  const int stride = 2048 * 256;
  for (; i < n4; i += stride) {
    const float4 v = reinterpret_cast<const float4*>(x)[i];
    u16x4 r;
    r[0] = f2b(v.x); r[1] = f2b(v.y); r[2] = f2b(v.z); r[3] = f2b(v.w);
    reinterpret_cast<u16x4*>(xb)[i] = r;
  }
}

// ---------------- kernel 2: int4 W -> bf16 W^T [N][K] ----------------
__global__ __launch_bounds__(256) void dequant_w_kernel(const int* __restrict__ pw,
                                                        const float* __restrict__ sc,
                                                        const float* __restrict__ zr,
                                                        u16* __restrict__ wbt) {
  __shared__ int tile[64][65];
  const int t = threadIdx.x;
  const int o0 = blockIdx.x * 64;
  const int kw0 = blockIdx.y * 64;
#pragma unroll
  for (int r = 0; r < 16; ++r) {
    const int kw = r * 4 + (t >> 6);
    const int o = t & 63;
    tile[kw][o] = pw[(kw0 + kw) * N_DIM + o0 + o];
  }
  __syncthreads();
  const int kwl = t & 63;
  const int g = (kw0 + kwl) >> 4;
  const int obase = (t >> 6) * 16;
  for (int it = 0; it < 16; ++it) {
    const int ol = obase + it;
    const int o = o0 + ol;
    const float s = sc[o * 32 + g];
    const float z = zr[o * 32 + g];
    const float b = -z * s;
    const int word = tile[kwl][ol];
    u16x8 r;
#pragma unroll
    for (int j = 0; j < 8; ++j) {
      const float q = (float)((word >> (4 * j)) & 0xF);
      r[j] = f2b(fmaf(q, s, b));
    }
    *reinterpret_cast<u16x8*>(&wbt[(size_t)o * K_DIM + (size_t)(kw0 + kwl) * 8]) = r;
  }
}

// ---------------- kernel 3: 256x256 1-barrier/tile bf16 MFMA GEMM ----------------
// 512 thr = 8 waves (2M x 4N); per wave 128x64 out = 8x4 frags of 16x16x32.
// LDS: 2 buf x (A[256][64] + B[256][64]) bf16 = 128 KiB, 16B-slot swizzle ^(row&7).

#define WAITL0                                               \
  asm volatile("s_waitcnt lgkmcnt(0)" ::: "memory");         \
  __builtin_amdgcn_sched_barrier(0)
#define WAITV(n)                                             \
  asm volatile("s_waitcnt vmcnt(" #n ")" ::: "memory");      \
  __builtin_amdgcn_sched_barrier(0)
#define BAR __builtin_amdgcn_s_barrier()

__global__ __launch_bounds__(512, 2) void gemm_kernel(const u16* __restrict__ xb,
                                                      const u16* __restrict__ wbt,
                                                      float* __restrict__ out) {
  __shared__ __align__(16) u16 lds[2][2][BM * BK];  // 131072 B

  const int tid = threadIdx.x;
  const int w = tid >> 6;
  const int l = tid & 63;
  const int wm = w >> 2;  // 0..1
  const int wn = w & 3;   // 0..3

  // bijective XCD swizzle: 1376 = 8*172
  const int bid = blockIdx.x;
  const int wg = (bid & 7) * 172 + (bid >> 3);
  const int NT = N_DIM / BN;  // 43
  const int m0 = (wg / NT) * BM;
  const int n0 = (wg % NT) * BN;

  // ---- staging: quarter (64 rows x 64 cols); thread -> row=q*64+(tid>>3), slot=tid&7
  const int sr = tid >> 3;                       // 0..63
  const int scc = ((tid & 7) ^ (sr & 7)) * 8;    // involution slot^(row&7)
  const u16* srcA = xb + (size_t)(m0 + sr) * K_DIM + scc;
  const u16* srcB = wbt + (size_t)(n0 + sr) * K_DIM + scc;

#define STAGEQ(buf, op, q, t)                                                  \
  __builtin_amdgcn_global_load_lds(                                            \
      gcvp(((op) ? srcB : srcA) + (size_t)((q) * 64) * K_DIM + (t) * 64),      \
      svp(&lds[buf][op][((q) * 64 + w * 8) * 64]), 16, 0, 0)

  // ---- fragment bases (elem offsets, swizzled read side); kk=1 addr = kk=0 ^ 32
  const int swz = ((l >> 4) ^ (l & 7)) * 8;
  const int baseA = (wm * 128 + (l & 15)) * 64 + swz;
  const int baseB = 16384 + (wn * 64 + (l & 15)) * 64 + swz;
  const u16* lp = &lds[0][0][0];

  bf16x8 a[4][2], b0[2][2], b1[2][2];

#define LDA(cb, S)                                                                      \
  do {                                                                                  \
    _Pragma("unroll") for (int _m = 0; _m < 4; ++_m) {                                  \
      const int _e = (cb) + baseA + ((S) * 4 + _m) * 1024;                              \
      a[_m][0] = *reinterpret_cast<const bf16x8*>(&lp[_e]);                             \
      a[_m][1] = *reinterpret_cast<const bf16x8*>(&lp[_e ^ 32]);                        \
    }                                                                                   \
  } while (0)
#define LDB(cb, BA, U)                                                                  \
  do {                                                                                  \
    _Pragma("unroll") for (int _n = 0; _n < 2; ++_n) {                                  \
      const int _e = (cb) + baseB + ((U) * 2 + _n) * 1024;                              \
      BA[_n][0] = *reinterpret_cast<const bf16x8*>(&lp[_e]);                            \
      BA[_n][1] = *reinterpret_cast<const bf16x8*>(&lp[_e ^ 32]);                       \
    }                                                                                   \
  } while (0)

  floatx4 acc[8][4] = {};

#define QMFMA(S, BA, U)                                                                 \
  do {                                                                                  \
    __builtin_amdgcn_s_setprio(1);                                                     \
    _Pragma("unroll") for (int _m = 0; _m < 4; ++_m)                                    \
      _Pragma("unroll") for (int _n = 0; _n < 2; ++_n)                                  \
        _Pragma("unroll") for (int _k = 0; _k < 2; ++_k)                                \
          acc[(S) * 4 + _m][(U) * 2 + _n] = __builtin_amdgcn_mfma_f32_16x16x32_bf16(    \
              a[_m][_k], BA[_n][_k], acc[(S) * 4 + _m][(U) * 2 + _n], 0, 0, 0);         \
    __builtin_amdgcn_s_setprio(0);                                                     \
  } while (0)

  // ---- prologue: stage tile 0 (8 loads) into buf 0 ----
  STAGEQ(0, 1, 2, 0); STAGEQ(0, 1, 3, 0);
  STAGEQ(0, 1, 0, 0); STAGEQ(0, 1, 1, 0);
  STAGEQ(0, 0, 0, 0); STAGEQ(0, 0, 1, 0); STAGEQ(0, 0, 2, 0); STAGEQ(0, 0, 3, 0);

  // ---- main loop: ONE WAITV(0) + ONE BAR per K-tile (at p0 top) ----
  // At t-p0 top the queue holds exactly tile t's 8 loads (t+1's not yet issued).
  // BAR-passage proves all waves drained their t-1 reads (per-phase WAITL0
  // precedes each MFMA precedes BAR arrival) -> every stage after BAR is WAR-safe.
  // p1-p3: no cross-wave sync; waves drift up to a full tile.
#pragma unroll 2
  for (int t = 0; t < NKT - 1; ++t) {
    const int buf = t & 1;
    const int sb = buf ^ 1;
    const int cb = buf * 32768;
    // p0: confirm tile t + publish; stage B-q2,q3[t+1]; read A-S0 + B-U0
    WAITV(0); BAR;
    STAGEQ(sb, 1, 2, t + 1); STAGEQ(sb, 1, 3, t + 1);
    LDA(cb, 0);
    LDB(cb, b0, 0);
    WAITL0;
    QMFMA(0, b0, 0);
    // p1: stage B-q0,q1 + A-q0 [t+1]; read B-U1
    STAGEQ(sb, 1, 0, t + 1); STAGEQ(sb, 1, 1, t + 1); STAGEQ(sb, 0, 0, t + 1);
    LDB(cb, b1, 1);
    WAITL0;
    QMFMA(0, b1, 1);
    // p2: stage A-q1,q2,q3 [t+1]; read A-S1
    STAGEQ(sb, 0, 1, t + 1); STAGEQ(sb, 0, 2, t + 1); STAGEQ(sb, 0, 3, t + 1);
    LDA(cb, 1);
    WAITL0;
    QMFMA(1, b0, 0);
    // p3: MFMA only
    QMFMA(1, b1, 1);
  }

  // ---- peel t = NKT-1 (buf=1): no stages; single drain+publish ----
  {
    const int cb = 32768;
    WAITV(0); BAR;
    LDA(cb, 0);
    LDB(cb, b0, 0);
    WAITL0;
    QMFMA(0, b0, 0);
    LDB(cb, b1, 1);
    WAITL0;
    QMFMA(0, b1, 1);
    LDA(cb, 1);
    WAITL0;
    QMFMA(1, b0, 0);
    QMFMA(1, b1, 1);
  }

  // ---- epilogue: C/D map col = l&15, row = (l>>4)*4 + j (verified R1/R2) ----
  const int orow0 = m0 + wm * 128 + (l >> 4) * 4;
  const int ocol0 = n0 + wn * 64 + (l & 15);
#pragma unroll
  for (int mi = 0; mi < 8; ++mi)
#pragma unroll
    for (int j = 0; j < 4; ++j) {
      float* op = out + (size_t)(orow0 + mi * 16 + j) * N_DIM + ocol0;
#pragma unroll
      for (int ni = 0; ni < 4; ++ni) op[ni * 16] = acc[mi][ni][j];
    }
}

// ---------------- fallback: fly-dequant (ws too small) ----------------
__global__ __launch_bounds__(256) void gemm_naive(const float* __restrict__ x,
                                                  const int* __restrict__ pw,
                                                  const float* __restrict__ sc,
                                                  const float* __restrict__ zr,
                                                  float* __restrict__ out) {
  const int idx = blockIdx.x * 256 + threadIdx.x;
  if (idx >= M_DIM * N_DIM) return;
  const int m = idx / N_DIM, o = idx % N_DIM;
  const float* xr = x + (size_t)m * K_DIM;
  float acc = 0.f;
  for (int g = 0; g < 32; ++g) {
    const float s = sc[o * 32 + g];
    const float z = zr[o * 32 + g];
    const float b = -z * s;
    for (int kw = g * 16; kw < g * 16 + 16; ++kw) {
      const int word = pw[kw * N_DIM + o];
#pragma unroll
      for (int j = 0; j < 8; ++j) {
        const float q = (float)((word >> (4 * j)) & 0xF);
        acc += xr[kw * 8 + j] * fmaf(q, s, b);
      }
    }
  }
  out[idx] = acc;
}

extern "C" void kernel_launch(void* const* d_in, const int* in_sizes, int n_in,
                              void* d_out, int out_size, void* d_ws, size_t ws_size,
                              hipStream_t stream) {
  (void)in_sizes; (void)n_in; (void)out_size;
  const float* x = (const float*)d_in[0];
  const int* pw = (const int*)d_in[1];
  const float* sc = (const float*)d_in[2];
  const float* zr = (const float*)d_in[3];
  float* out = (float*)d_out;

  const size_t need = ((size_t)M_DIM * K_DIM + (size_t)N_DIM * K_DIM) * 2;
  if (ws_size >= need) {
    u16* xb = (u16*)d_ws;
    u16* wbt = xb + (size_t)M_DIM * K_DIM;
    cvt_x_kernel<<<2048, 256, 0, stream>>>(x, xb);
    dequant_w_kernel<<<dim3(N_DIM / 64, (K_DIM / 8) / 64), 256, 0, stream>>>(pw, sc, zr, wbt);
    gemm_kernel<<<(M_DIM / BM) * (N_DIM / BN), 512, 0, stream>>>(xb, wbt, out);
  } else {
    gemm_naive<<<(M_DIM * N_DIM + 255) / 256, 256, 0, stream>>>(x, pw, sc, zr, out);
  }
}

// Round 12
// 687.612 us; speedup vs baseline: 1.1379x; 1.1379x over previous
//
#include <hip/hip_runtime.h>

// WeightOnlyInt4Linear: out[8192,11008] = x[8192,4096] @ dequant(packed int4 W)
// (1) x -> bf16, (2) W int4 -> bf16 [N][K] transposed, (3) bf16 MFMA GEMM.
// R12: 256x128 tile, 256 thr (4 waves 2Mx2N), SINGLE-buffer 48 KB LDS ->
// 2 blocks/CU co-resident (regs cap waves at 8/CU; now split across 2 drifting
// blocks) and grid 2752=8*344 -> tail 10.4%->2.3%. Phase-top waits (R9-proven).
// 12 loads/tile ledger: p0 WAITV(6) retires AS0+BU0[t]; p1 WAITV(4) retires
// BU1[t]; p2 WAITV(6) retires AS1[t]. Stages 6/2/4 at p1/p2/p3 post-BAR.

#define M_DIM 8192
#define K_DIM 4096
#define N_DIM 11008
#define BM 256
#define BN 128
#define BK 64
#define NKT (K_DIM / BK)  // 64

typedef unsigned short u16;
typedef __bf16 bf16x8 __attribute__((ext_vector_type(8)));
typedef float floatx4 __attribute__((ext_vector_type(4)));
typedef u16 u16x8 __attribute__((ext_vector_type(8)));
typedef u16 u16x4 __attribute__((ext_vector_type(4)));

typedef __attribute__((address_space(1))) const void* gcvp;
typedef __attribute__((address_space(3))) void* svp;

static __device__ __forceinline__ u16 f2b(float f) {
  union { float f; unsigned u; } v;
  v.f = f;
  unsigned r = v.u + 0x7FFFu + ((v.u >> 16) & 1u);  // RNE, finite inputs
  return (u16)(r >> 16);
}

// ---------------- kernel 1: x f32 -> bf16 ----------------
__global__ __launch_bounds__(256) void cvt_x_kernel(const float* __restrict__ x,
                                                    u16* __restrict__ xb) {
  int i = blockIdx.x * 256 + threadIdx.x;
  const int n4 = (M_DIM * K_DIM) / 4;
  const int stride = 2048 * 256;
  for (; i < n4; i += stride) {
    const float4 v = reinterpret_cast<const float4*>(x)[i];
    u16x4 r;
    r[0] = f2b(v.x); r[1] = f2b(v.y); r[2] = f2b(v.z); r[3] = f2b(v.w);
    reinterpret_cast<u16x4*>(xb)[i] = r;
  }
}

// ---------------- kernel 2: int4 W -> bf16 W^T [N][K] ----------------
__global__ __launch_bounds__(256) void dequant_w_kernel(const int* __restrict__ pw,
                                                        const float* __restrict__ sc,
                                                        const float* __restrict__ zr,
                                                        u16* __restrict__ wbt) {
  __shared__ int tile[64][65];
  const int t = threadIdx.x;
  const int o0 = blockIdx.x * 64;
  const int kw0 = blockIdx.y * 64;
#pragma unroll
  for (int r = 0; r < 16; ++r) {
    const int kw = r * 4 + (t >> 6);
    const int o = t & 63;
    tile[kw][o] = pw[(kw0 + kw) * N_DIM + o0 + o];
  }
  __syncthreads();
  const int kwl = t & 63;
  const int g = (kw0 + kwl) >> 4;
  const int obase = (t >> 6) * 16;
  for (int it = 0; it < 16; ++it) {
    const int ol = obase + it;
    const int o = o0 + ol;
    const float s = sc[o * 32 + g];
    const float z = zr[o * 32 + g];
    const float b = -z * s;
    const int word = tile[kwl][ol];
    u16x8 r;
#pragma unroll
    for (int j = 0; j < 8; ++j) {
      const float q = (float)((word >> (4 * j)) & 0xF);
      r[j] = f2b(fmaf(q, s, b));
    }
    *reinterpret_cast<u16x8*>(&wbt[(size_t)o * K_DIM + (size_t)(kw0 + kwl) * 8]) = r;
  }
}

// ---------------- kernel 3: 256x128 single-buffer bf16 MFMA GEMM ----------------
// 256 thr = 4 waves (wm=w>>1, wn=w&1); per wave 128x64 out = 8x4 frags 16x16x32
// (frag/acc layout IDENTICAL to R7). LDS: A[256][64] (32KB) + B[128][64] (16KB),
// 16B-slot swizzle ^(row&7). Stage unit = 32 rows x 64 cols (256 thr x 16B).
// A units 0..7 (32 rows each): AS0 = {0,1,4,5} (rows 0-63,128-191, read p0);
// AS1 = {2,3,6,7} (read p2). B units 0..3: BU0 = {0,2} (p0), BU1 = {1,3} (p1).

#define WAITL0                                               \
  asm volatile("s_waitcnt lgkmcnt(0)" ::: "memory");         \
  __builtin_amdgcn_sched_barrier(0)
#define WAITV(n)                                             \
  asm volatile("s_waitcnt vmcnt(" #n ")" ::: "memory");      \
  __builtin_amdgcn_sched_barrier(0)
#define BAR __builtin_amdgcn_s_barrier()

__global__ __launch_bounds__(256, 2) void gemm_kernel(const u16* __restrict__ xb,
                                                      const u16* __restrict__ wbt,
                                                      float* __restrict__ out) {
  __shared__ __align__(16) u16 lds[(BM + BN) * BK];  // 49152 B: A @0, B @16384

  const int tid = threadIdx.x;
  const int w = tid >> 6;
  const int l = tid & 63;
  const int wm = w >> 1;  // 0..1
  const int wn = w & 1;   // 0..1

  // bijective XCD swizzle: 2752 = 8*344
  const int bid = blockIdx.x;
  const int wg = (bid & 7) * 344 + (bid >> 3);
  const int NT = N_DIM / BN;  // 86
  const int m0 = (wg / NT) * BM;
  const int n0 = (wg % NT) * BN;

  // ---- staging: unit = 32 rows; thread -> row = u*32 + (tid>>3), slot = tid&7
  const int sr = tid >> 3;                       // 0..31
  const int scc = ((tid & 7) ^ (sr & 7)) * 8;    // involution slot^(row&7)
  const u16* srcA = xb + (size_t)(m0 + sr) * K_DIM + scc;
  const u16* srcB = wbt + (size_t)(n0 + sr) * K_DIM + scc;

#define STAGEU(op, u, t)                                                       \
  __builtin_amdgcn_global_load_lds(                                            \
      gcvp(((op) ? srcB : srcA) + (size_t)((u) * 32) * K_DIM + (t) * 64),      \
      svp(&lds[(op) * 16384 + ((u) * 32 + w * 8) * 64]), 16, 0, 0)

  // ---- fragment bases (identical formulas to R7); kk=1 addr = kk=0 ^ 32
  const int swz = ((l >> 4) ^ (l & 7)) * 8;
  const int baseA = (wm * 128 + (l & 15)) * 64 + swz;
  const int baseB = 16384 + (wn * 64 + (l & 15)) * 64 + swz;
  const u16* lp = &lds[0];

  bf16x8 a[4][2], b0[2][2], b1[2][2];

#define LDA(S)                                                                          \
  do {                                                                                  \
    _Pragma("unroll") for (int _m = 0; _m < 4; ++_m) {                                  \
      const int _e = baseA + ((S) * 4 + _m) * 1024;                                     \
      a[_m][0] = *reinterpret_cast<const bf16x8*>(&lp[_e]);                             \
      a[_m][1] = *reinterpret_cast<const bf16x8*>(&lp[_e ^ 32]);                        \
    }                                                                                   \
  } while (0)
#define LDB(BA, U)                                                                      \
  do {                                                                                  \
    _Pragma("unroll") for (int _n = 0; _n < 2; ++_n) {                                  \
      const int _e = baseB + ((U) * 2 + _n) * 1024;                                     \
      BA[_n][0] = *reinterpret_cast<const bf16x8*>(&lp[_e]);                            \
      BA[_n][1] = *reinterpret_cast<const bf16x8*>(&lp[_e ^ 32]);                       \
    }                                                                                   \
  } while (0)

  floatx4 acc[8][4] = {};

#define QMFMA(S, BA, U)                                                                 \
  do {                                                                                  \
    __builtin_amdgcn_s_setprio(1);                                                     \
    _Pragma("unroll") for (int _m = 0; _m < 4; ++_m)                                    \
      _Pragma("unroll") for (int _n = 0; _n < 2; ++_n)                                  \
        _Pragma("unroll") for (int _k = 0; _k < 2; ++_k)                                \
          acc[(S) * 4 + _m][(U) * 2 + _n] = __builtin_amdgcn_mfma_f32_16x16x32_bf16(    \
              a[_m][_k], BA[_n][_k], acc[(S) * 4 + _m][(U) * 2 + _n], 0, 0, 0);         \
    __builtin_amdgcn_s_setprio(0);                                                     \
  } while (0)

  // ---- prologue: tile 0 in ledger order: AS0+BU0 (6), BU1 (2), AS1 (4) ----
  STAGEU(0, 0, 0); STAGEU(0, 1, 0); STAGEU(0, 4, 0); STAGEU(0, 5, 0);
  STAGEU(1, 0, 0); STAGEU(1, 2, 0);
  STAGEU(1, 1, 0); STAGEU(1, 3, 0);
  STAGEU(0, 2, 0); STAGEU(0, 3, 0); STAGEU(0, 6, 0); STAGEU(0, 7, 0);

  // ---- main loop: t in [0, NKT-2]; waits at phase top, reads after ----
  // Ledger: p0 top outstanding=12 -> WAITV(6) retires AS0[t],BU0[t].
  //         p1 top 6 -> WAITV(4) retires BU1[t]; stage +6 -> 10.
  //         p2 top 10 -> WAITV(6) retires AS1[t]; stage +2 -> 8.
  //         p3: stage +4 -> 12.  WAR: every stage follows the BAR after its
  //         region's last-read WAITL0 (p0->p1, p1->p2, p2->p3).
  for (int t = 0; t < NKT - 1; ++t) {
    // p0: confirm+publish AS0,BU0[t]; read A-S0 + B-U0
    WAITV(6); BAR;
    LDA(0);
    LDB(b0, 0);
    WAITL0;
    QMFMA(0, b0, 0);
    // p1: confirm BU1[t]; BAR also proves p0 reads drained; stage AS0+BU0[t+1]
    WAITV(4); BAR;
    STAGEU(0, 0, t + 1); STAGEU(0, 1, t + 1); STAGEU(0, 4, t + 1); STAGEU(0, 5, t + 1);
    STAGEU(1, 0, t + 1); STAGEU(1, 2, t + 1);
    LDB(b1, 1);
    WAITL0;
    QMFMA(0, b1, 1);
    // p2: confirm AS1[t]; BAR proves p1 reads drained; stage BU1[t+1]
    WAITV(6); BAR;
    STAGEU(1, 1, t + 1); STAGEU(1, 3, t + 1);
    LDA(1);
    WAITL0;
    QMFMA(1, b0, 0);
    // p3: BAR proves p2 reads drained; stage AS1[t+1]
    BAR;
    STAGEU(0, 2, t + 1); STAGEU(0, 3, t + 1); STAGEU(0, 6, t + 1); STAGEU(0, 7, t + 1);
    QMFMA(1, b1, 1);
  }

  // ---- peel t = NKT-1: no stages; drain 6 -> 4 -> 0 ----
  {
    WAITV(6); BAR;
    LDA(0);
    LDB(b0, 0);
    WAITL0;
    QMFMA(0, b0, 0);
    WAITV(4); BAR;
    LDB(b1, 1);
    WAITL0;
    QMFMA(0, b1, 1);
    WAITV(0); BAR;
    LDA(1);
    WAITL0;
    QMFMA(1, b0, 0);
    QMFMA(1, b1, 1);
  }

  // ---- epilogue: C/D map col = l&15, row = (l>>4)*4 + j (verified R1/R2) ----
  const int orow0 = m0 + wm * 128 + (l >> 4) * 4;
  const int ocol0 = n0 + wn * 64 + (l & 15);
#pragma unroll
  for (int mi = 0; mi < 8; ++mi)
#pragma unroll
    for (int j = 0; j < 4; ++j) {
      float* op = out + (size_t)(orow0 + mi * 16 + j) * N_DIM + ocol0;
#pragma unroll
      for (int ni = 0; ni < 4; ++ni) op[ni * 16] = acc[mi][ni][j];
    }
}

// ---------------- fallback: fly-dequant (ws too small) ----------------
__global__ __launch_bounds__(256) void gemm_naive(const float* __restrict__ x,
                                                  const int* __restrict__ pw,
                                                  const float* __restrict__ sc,
                                                  const float* __restrict__ zr,
                                                  float* __restrict__ out) {
  const int idx = blockIdx.x * 256 + threadIdx.x;
  if (idx >= M_DIM * N_DIM) return;
  const int m = idx / N_DIM, o = idx % N_DIM;
  const float* xr = x + (size_t)m * K_DIM;
  float acc = 0.f;
  for (int g = 0; g < 32; ++g) {
    const float s = sc[o * 32 + g];
    const float z = zr[o * 32 + g];
    const float b = -z * s;
    for (int kw = g * 16; kw < g * 16 + 16; ++kw) {
      const int word = pw[kw * N_DIM + o];
#pragma unroll
      for (int j = 0; j < 8; ++j) {
        const float q = (float)((word >> (4 * j)) & 0xF);
        acc += xr[kw * 8 + j] * fmaf(q, s, b);
      }
    }
  }
  out[idx] = acc;
}

extern "C" void kernel_launch(void* const* d_in, const int* in_sizes, int n_in,
                              void* d_out, int out_size, void* d_ws, size_t ws_size,
                              hipStream_t stream) {
  (void)in_sizes; (void)n_in; (void)out_size;
  const float* x = (const float*)d_in[0];
  const int* pw = (const int*)d_in[1];
  const float* sc = (const float*)d_in[2];
  const float* zr = (const float*)d_in[3];
  float* out = (float*)d_out;

  const size_t need = ((size_t)M_DIM * K_DIM + (size_t)N_DIM * K_DIM) * 2;
  if (ws_size >= need) {
    u16* xb = (u16*)d_ws;
    u16* wbt = xb + (size_t)M_DIM * K_DIM;
    cvt_x_kernel<<<2048, 256, 0, stream>>>(x, xb);
    dequant_w_kernel<<<dim3(N_DIM / 64, (K_DIM / 8) / 64), 256, 0, stream>>>(pw, sc, zr, wbt);
    gemm_kernel<<<(M_DIM / BM) * (N_DIM / BN), 256, 0, stream>>>(xb, wbt, out);
  } else {
    gemm_naive<<<(M_DIM * N_DIM + 255) / 256, 256, 0, stream>>>(x, pw, sc, zr, out);
  }
}